// Round 10
// baseline (132.177 us; speedup 1.0000x reference)
//
#include <hip/hip_runtime.h>
#include <hip/hip_cooperative_groups.h>

namespace cg = cooperative_groups;

#define N 1536
#define RI 6      // rows per block (256 * 6 = 1536)
#define G  16     // j-groups (one per wave)
#define JPG (N / G)   // 96 j per wave, contiguous
#define JB 8      // load batch depth

// One cooperative kernel: enc -> grid.sync -> msg -> update MLP -> heads.
// 256 blocks x 1024 threads, 1 block/CU.
__global__ __launch_bounds__(1024) void fused_kernel(
    const float* __restrict__ x,
    const float* __restrict__ W1, const float* __restrict__ b1,
    const float* __restrict__ W2, const float* __restrict__ b2,
    const float* __restrict__ Wm, const float* __restrict__ bm,
    const float* __restrict__ Wu1, const float* __restrict__ bu1,
    const float* __restrict__ Wu2, const float* __restrict__ bu2,
    const float* __restrict__ Wmean, const float* __restrict__ bmean,
    const float* __restrict__ Wv, const float* __restrict__ bv,
    const float* __restrict__ log_std,
    float* __restrict__ p, float* __restrict__ out)
{
    __shared__ union SharedU {
        struct { float sW2[64 * 64]; float sWm[64 * 64]; } ph1;   // 32 KB
        struct { float red[G][RI][64]; float part[8][RI][128]; } ph2; // 48 KB
    } smem;
    __shared__ float hu[RI][128];   // h | msgs, later final u   (3 KB)
    __shared__ float u1s[RI][128];  // buf1 (phase1), u1 (phase3) (3 KB)
    __shared__ float qs[RI][64];    // q = p_own - bm             (1.5 KB)

    int t = threadIdx.x;
    int c = t & 63, g = t >> 6;     // lane, wave
    int i0 = blockIdx.x * RI;

    // ================= phase 1: encoder for own 6 rows =================
    {
        const float4* W2v = (const float4*)W2;
        const float4* Wmv = (const float4*)Wm;
        float4* s2 = (float4*)smem.ph1.sW2;
        float4* sm = (float4*)smem.ph1.sWm;
        s2[t] = W2v[t];
        sm[t] = Wmv[t];
    }
    if (g < RI) {
        int row = i0 + g;
        float4 xv = ((const float4*)x)[row];
        float h1 = xv.x * W1[0 * 64 + c] + xv.y * W1[1 * 64 + c]
                 + xv.z * W1[2 * 64 + c] + xv.w * W1[3 * 64 + c] + b1[c];
        u1s[g][c] = fmaxf(0.f, h1);          // buf1 (own-wave RAW ok)
    }
    __syncthreads();   // sW2/sWm staged; buf1 visible

    if (g < RI) {
        float h2 = b2[c];
        #pragma unroll
        for (int k = 0; k < 64; ++k)
            h2 = fmaf(u1s[g][k], smem.ph1.sW2[k * 64 + c], h2);
        h2 = fmaxf(0.f, h2);
        hu[g][c] = h2;                       // h stays in LDS (own-wave RAW)

        float pv = 0.f;
        #pragma unroll
        for (int k = 0; k < 64; ++k)
            pv = fmaf(hu[g][k], smem.ph1.sWm[k * 64 + c], pv);
        p[(i0 + g) * 64 + c] = pv;           // only p goes global
        qs[g][c] = pv - bm[c];
    }

    __threadfence();
    cg::this_grid().sync();                  // p visible device-wide

    // ================= phase 2: message pass (round-4 pattern) =================
    float q[RI];
    #pragma unroll
    for (int r = 0; r < RI; ++r) q[r] = qs[r][c];

    const float* pw = p + g * JPG * 64 + c;  // wave-contiguous j chunk
    float acc[RI];
    #pragma unroll
    for (int r = 0; r < RI; ++r) acc[r] = 0.f;

    float pj0[JB], pj1[JB];
    #pragma unroll
    for (int u = 0; u < JB; ++u) pj0[u] = pw[u * 64];

    #pragma unroll
    for (int jj = 0; jj < JPG / JB; ++jj) {  // 12 batches of 8
        if (jj + 1 < JPG / JB) {
            if ((jj & 1) == 0) {
                #pragma unroll
                for (int u = 0; u < JB; ++u) pj1[u] = pw[((jj + 1) * JB + u) * 64];
            } else {
                #pragma unroll
                for (int u = 0; u < JB; ++u) pj0[u] = pw[((jj + 1) * JB + u) * 64];
            }
        }
        if ((jj & 1) == 0) {
            #pragma unroll
            for (int u = 0; u < JB; ++u) {
                #pragma unroll
                for (int r = 0; r < RI; ++r) acc[r] += fmaxf(pj0[u], q[r]);
            }
        } else {
            #pragma unroll
            for (int u = 0; u < JB; ++u) {
                #pragma unroll
                for (int r = 0; r < RI; ++r) acc[r] += fmaxf(pj1[u], q[r]);
            }
        }
    }
    #pragma unroll
    for (int r = 0; r < RI; ++r) smem.ph2.red[g][r][c] = acc[r];
    __syncthreads();

    // reduce 16 j-group partials; finalize msgs with max-trick correction
    if (t < RI * 64) {
        int r = t >> 6, cc = t & 63;
        float s = 0.f;
        #pragma unroll
        for (int gg = 0; gg < G; ++gg) s += smem.ph2.red[gg][r][cc];
        hu[r][64 + cc] = (s - (float)N * qs[r][cc]) * (1.0f / N);
    }
    __syncthreads();

    // ================= phase 3: update MLP + heads =================
    int ch = t & 127, kh = t >> 7;           // kh 0..7, k in [kh*16, kh*16+16)
    {
        float u1[RI];
        #pragma unroll
        for (int r = 0; r < RI; ++r) u1[r] = 0.f;
        #pragma unroll
        for (int k = kh * 16; k < kh * 16 + 16; ++k) {
            float w = Wu1[k * 128 + ch];
            #pragma unroll
            for (int r = 0; r < RI; ++r) u1[r] = fmaf(hu[r][k], w, u1[r]);
        }
        #pragma unroll
        for (int r = 0; r < RI; ++r) smem.ph2.part[kh][r][ch] = u1[r];
    }
    __syncthreads();
    if (t < RI * 128) {
        int r = t >> 7, cc = t & 127;
        float v = bu1[cc];
        #pragma unroll
        for (int kk = 0; kk < 8; ++kk) v += smem.ph2.part[kk][r][cc];
        u1s[r][cc] = fmaxf(0.f, v);
    }
    __syncthreads();
    {
        float u2[RI];
        #pragma unroll
        for (int r = 0; r < RI; ++r) u2[r] = 0.f;
        #pragma unroll
        for (int k = kh * 16; k < kh * 16 + 16; ++k) {
            float w = Wu2[k * 128 + ch];
            #pragma unroll
            for (int r = 0; r < RI; ++r) u2[r] = fmaf(u1s[r][k], w, u2[r]);
        }
        #pragma unroll
        for (int r = 0; r < RI; ++r) smem.ph2.part[kh][r][ch] = u2[r];
    }
    __syncthreads();
    if (t < RI * 128) {
        int r = t >> 7, cc = t & 127;
        float v = bu2[cc];
        #pragma unroll
        for (int kk = 0; kk < 8; ++kk) v += smem.ph2.part[kk][r][cc];
        hu[r][cc] = fmaxf(0.f, v);
    }
    __syncthreads();

    // heads: wave g < RI handles row g, 64-lane shuffle reduction
    if (g < RI) {
        int r = g, lane = c;
        float a  = hu[r][lane];
        float b2v = hu[r][lane + 64];
        float m0 = a * Wmean[lane * 2 + 0] + b2v * Wmean[(lane + 64) * 2 + 0];
        float m1 = a * Wmean[lane * 2 + 1] + b2v * Wmean[(lane + 64) * 2 + 1];
        float vv = a * Wv[lane]            + b2v * Wv[lane + 64];
        #pragma unroll
        for (int off = 32; off > 0; off >>= 1) {
            m0 += __shfl_down(m0, off);
            m1 += __shfl_down(m1, off);
            vv += __shfl_down(vv, off);
        }
        if (lane == 0) {
            int row = i0 + r;
            out[row * 2 + 0] = m0 + bmean[0];
            out[row * 2 + 1] = m1 + bmean[1];
            out[3074 + row]  = vv + bv[0];
        }
    }
    if (blockIdx.x == 0 && t < 2) {
        out[3072 + t] = expf(log_std[t]);
    }
}

extern "C" void kernel_launch(void* const* d_in, const int* in_sizes, int n_in,
                              void* d_out, int out_size, void* d_ws, size_t ws_size,
                              hipStream_t stream) {
    const float* x      = (const float*)d_in[0];
    const float* W1     = (const float*)d_in[1];
    const float* b1     = (const float*)d_in[2];
    const float* W2     = (const float*)d_in[3];
    const float* b2     = (const float*)d_in[4];
    const float* Wm     = (const float*)d_in[5];
    const float* bm     = (const float*)d_in[6];
    const float* Wu1    = (const float*)d_in[7];
    const float* bu1    = (const float*)d_in[8];
    const float* Wu2    = (const float*)d_in[9];
    const float* bu2    = (const float*)d_in[10];
    const float* Wmean  = (const float*)d_in[11];
    const float* bmean  = (const float*)d_in[12];
    const float* Wv     = (const float*)d_in[13];
    const float* bv     = (const float*)d_in[14];
    const float* log_std= (const float*)d_in[15];
    float* out = (float*)d_out;
    float* p   = (float*)d_ws;     // N*64

    void* args[] = {
        (void*)&x, (void*)&W1, (void*)&b1, (void*)&W2, (void*)&b2,
        (void*)&Wm, (void*)&bm, (void*)&Wu1, (void*)&bu1, (void*)&Wu2,
        (void*)&bu2, (void*)&Wmean, (void*)&bmean, (void*)&Wv, (void*)&bv,
        (void*)&log_std, (void*)&p, (void*)&out
    };
    hipLaunchCooperativeKernel((const void*)fused_kernel,
                               dim3(N / RI), dim3(1024), args, 0, stream);
}

// Round 11
// 24.051 us; speedup vs baseline: 5.4958x; 5.4958x over previous
//
#include <hip/hip_runtime.h>

#define N 1536

// ---------------- K1: node encoder + message projection ----------------
// 256 blocks x 512 threads; 6 rows/block, float4 weight staging.
__global__ __launch_bounds__(512) void enc_kernel(
    const float* __restrict__ x, const float* __restrict__ W1, const float* __restrict__ b1,
    const float* __restrict__ W2, const float* __restrict__ b2,
    const float* __restrict__ Wm,
    float* __restrict__ h, float* __restrict__ p)
{
    __shared__ float sW2[64 * 64];
    __shared__ float sWm[64 * 64];
    __shared__ float buf1[6][64];
    __shared__ float buf2[6][64];
    int t = threadIdx.x;
    int w = t >> 6, c = t & 63;
    int i0 = blockIdx.x * 6;

    {
        const float4* W2v = (const float4*)W2;
        const float4* Wmv = (const float4*)Wm;
        float4* s2 = (float4*)sW2;
        float4* sm = (float4*)sWm;
        #pragma unroll
        for (int i = t; i < 1024; i += 512) { s2[i] = W2v[i]; sm[i] = Wmv[i]; }
    }

    if (w < 6) {
        int row = i0 + w;
        float4 xv = ((const float4*)x)[row];
        float h1 = xv.x * W1[0 * 64 + c] + xv.y * W1[1 * 64 + c]
                 + xv.z * W1[2 * 64 + c] + xv.w * W1[3 * 64 + c] + b1[c];
        buf1[w][c] = fmaxf(0.f, h1);
    }
    __syncthreads();

    if (w < 6) {
        int row = i0 + w;
        float h2 = b2[c];
        #pragma unroll
        for (int k = 0; k < 64; ++k) h2 = fmaf(buf1[w][k], sW2[k * 64 + c], h2);
        h2 = fmaxf(0.f, h2);
        h[row * 64 + c] = h2;
        buf2[w][c] = h2;

        float pv = 0.f;
        #pragma unroll
        for (int k = 0; k < 64; ++k) pv = fmaf(buf2[w][k], sWm[k * 64 + c], pv);
        p[row * 64 + c] = pv;
    }
}

// ---------------- K2: fused message pass + update MLP + heads ----------------
// 256 blocks x 1024 threads (16 waves). RI=6 rows per block.
// msgs[i,c] = (1/N)*(sum_j max(p[j,c], q) - N*q), q = p[i,c]-bm[c]
// De-convoy: chunk and batch traversal rotated per block so 256 blocks
// don't hammer identical L2 addresses in lockstep.
#define RI 6     // rows per block  (256 * 6 = 1536)
#define G  16    // j-groups (one per wave)
#define JPG (N / G)   // 96 j's per chunk
#define JB 8     // load batch depth
#define NBATCH (JPG / JB)   // 12 batches per chunk
__global__ __launch_bounds__(1024) void msg_upd_kernel(
    const float* __restrict__ p, const float* __restrict__ bm,
    const float* __restrict__ h,
    const float* __restrict__ Wu1, const float* __restrict__ bu1,
    const float* __restrict__ Wu2, const float* __restrict__ bu2,
    const float* __restrict__ Wmean, const float* __restrict__ bmean,
    const float* __restrict__ Wv, const float* __restrict__ bv,
    const float* __restrict__ log_std,
    float* __restrict__ out)
{
    __shared__ float red[G][RI][64];     // 24 KB  (j-group partials)
    __shared__ float qs[RI][64];         // 1.5 KB (q values for finalize)
    __shared__ float hu[RI][128];        // 3 KB   ([h, msgs], reused for final u)
    __shared__ float u1s[RI][128];       // 3 KB
    __shared__ float part[8][RI][128];   // 24 KB  (k-split partials)

    int t = threadIdx.x;
    int c = t & 63, g = t >> 6;          // g in 0..15 (wave id)
    int bid = blockIdx.x;
    int i0 = bid * RI;

    // ---- phase A ----
    float bmc = bm[c];
    float q[RI];
    #pragma unroll
    for (int r = 0; r < RI; ++r) q[r] = p[(i0 + r) * 64 + c] - bmc;
    if (g == 0) {
        #pragma unroll
        for (int r = 0; r < RI; ++r) qs[r][c] = q[r];
    }

    // rotated chunk + rotated batch start (de-convoy across blocks)
    int gg = (g + bid) & 15;
    const float* pw = p + gg * JPG * 64 + c;
    int bb = (bid >> 4) % NBATCH;        // starting batch within chunk

    float acc[RI];
    #pragma unroll
    for (int r = 0; r < RI; ++r) acc[r] = 0.f;

    float pj0[JB], pj1[JB];
    #pragma unroll
    for (int u = 0; u < JB; ++u) pj0[u] = pw[(bb * JB + u) * 64];

    for (int it = 0; it < NBATCH; ++it) {
        int bbn = (bb + 1 == NBATCH) ? 0 : bb + 1;
        if (it + 1 < NBATCH) {
            if ((it & 1) == 0) {
                #pragma unroll
                for (int u = 0; u < JB; ++u) pj1[u] = pw[(bbn * JB + u) * 64];
            } else {
                #pragma unroll
                for (int u = 0; u < JB; ++u) pj0[u] = pw[(bbn * JB + u) * 64];
            }
        }
        if ((it & 1) == 0) {
            #pragma unroll
            for (int u = 0; u < JB; ++u) {
                #pragma unroll
                for (int r = 0; r < RI; ++r) acc[r] += fmaxf(pj0[u], q[r]);
            }
        } else {
            #pragma unroll
            for (int u = 0; u < JB; ++u) {
                #pragma unroll
                for (int r = 0; r < RI; ++r) acc[r] += fmaxf(pj1[u], q[r]);
            }
        }
        bb = bbn;
    }
    #pragma unroll
    for (int r = 0; r < RI; ++r) red[g][r][c] = acc[r];

    // stage h rows into hu[:, 0:64] (384 entries) with spare waves
    if (t >= 512 && t < 512 + RI * 64) {
        int tt = t - 512;
        hu[tt >> 6][tt & 63] = h[(i0 + (tt >> 6)) * 64 + (tt & 63)];
    }
    __syncthreads();

    // reduce 16 j-group partials, finalize with max-trick correction
    if (t < RI * 64) {
        int r = t >> 6, cc = t & 63;
        float s = 0.f;
        #pragma unroll
        for (int gg2 = 0; gg2 < G; ++gg2) s += red[gg2][r][cc];
        hu[r][64 + cc] = (s - (float)N * qs[r][cc]) * (1.0f / N);
    }
    __syncthreads();

    // ---- phase B: update MLP, k split across 8 groups of 16 ----
    int ch = t & 127, kh = t >> 7;
    {
        float u1[RI];
        #pragma unroll
        for (int r = 0; r < RI; ++r) u1[r] = 0.f;
        #pragma unroll
        for (int k = kh * 16; k < kh * 16 + 16; ++k) {
            float w = Wu1[k * 128 + ch];
            #pragma unroll
            for (int r = 0; r < RI; ++r) u1[r] = fmaf(hu[r][k], w, u1[r]);
        }
        #pragma unroll
        for (int r = 0; r < RI; ++r) part[kh][r][ch] = u1[r];
    }
    __syncthreads();
    if (t < RI * 128) {
        int r = t >> 7, cc = t & 127;
        float v = bu1[cc];
        #pragma unroll
        for (int kk = 0; kk < 8; ++kk) v += part[kk][r][cc];
        u1s[r][cc] = fmaxf(0.f, v);
    }
    __syncthreads();
    {
        float u2[RI];
        #pragma unroll
        for (int r = 0; r < RI; ++r) u2[r] = 0.f;
        #pragma unroll
        for (int k = kh * 16; k < kh * 16 + 16; ++k) {
            float w = Wu2[k * 128 + ch];
            #pragma unroll
            for (int r = 0; r < RI; ++r) u2[r] = fmaf(u1s[r][k], w, u2[r]);
        }
        #pragma unroll
        for (int r = 0; r < RI; ++r) part[kh][r][ch] = u2[r];
    }
    __syncthreads();
    if (t < RI * 128) {
        int r = t >> 7, cc = t & 127;
        float v = bu2[cc];
        #pragma unroll
        for (int kk = 0; kk < 8; ++kk) v += part[kk][r][cc];
        hu[r][cc] = fmaxf(0.f, v);
    }
    __syncthreads();

    // ---- heads: wave g < RI handles row g, 64-lane shuffle reduction ----
    if (g < RI) {
        int r = g, lane = c;
        float a  = hu[r][lane];
        float b2 = hu[r][lane + 64];
        float m0 = a * Wmean[lane * 2 + 0] + b2 * Wmean[(lane + 64) * 2 + 0];
        float m1 = a * Wmean[lane * 2 + 1] + b2 * Wmean[(lane + 64) * 2 + 1];
        float vv = a * Wv[lane]            + b2 * Wv[lane + 64];
        #pragma unroll
        for (int off = 32; off > 0; off >>= 1) {
            m0 += __shfl_down(m0, off);
            m1 += __shfl_down(m1, off);
            vv += __shfl_down(vv, off);
        }
        if (lane == 0) {
            int row = i0 + r;
            out[row * 2 + 0] = m0 + bmean[0];
            out[row * 2 + 1] = m1 + bmean[1];
            out[3074 + row]  = vv + bv[0];
        }
    }
    if (blockIdx.x == 0 && t < 2) {
        out[3072 + t] = expf(log_std[t]);
    }
}

extern "C" void kernel_launch(void* const* d_in, const int* in_sizes, int n_in,
                              void* d_out, int out_size, void* d_ws, size_t ws_size,
                              hipStream_t stream) {
    const float* x      = (const float*)d_in[0];
    const float* W1     = (const float*)d_in[1];
    const float* b1     = (const float*)d_in[2];
    const float* W2     = (const float*)d_in[3];
    const float* b2     = (const float*)d_in[4];
    const float* Wm     = (const float*)d_in[5];
    const float* bm     = (const float*)d_in[6];
    const float* Wu1    = (const float*)d_in[7];
    const float* bu1    = (const float*)d_in[8];
    const float* Wu2    = (const float*)d_in[9];
    const float* bu2    = (const float*)d_in[10];
    const float* Wmean  = (const float*)d_in[11];
    const float* bmean  = (const float*)d_in[12];
    const float* Wv     = (const float*)d_in[13];
    const float* bv     = (const float*)d_in[14];
    const float* log_std= (const float*)d_in[15];
    float* out = (float*)d_out;

    float* ws = (float*)d_ws;
    float* h  = ws;              // N*64
    float* p  = ws + N * 64;     // N*64

    enc_kernel<<<N / 6, 512, 0, stream>>>(x, W1, b1, W2, b2, Wm, h, p);
    msg_upd_kernel<<<N / RI, 1024, 0, stream>>>(p, bm, h, Wu1, bu1, Wu2, bu2,
                                                Wmean, bmean, Wv, bv, log_std, out);
}